// Round 7
// baseline (439.817 us; speedup 1.0000x reference)
//
#include <hip/hip_runtime.h>

// TemporalAttentionBlock: B=128,S=64,D=1024,H=16,HD=64,FFN=4096
// Pipeline: cvt5(x,w*)->bf16 | qkv GEMM | attention(MFMA) | out-proj GEMM |
//           LN1 | FFN1 GEMM (gelu) | FFN2 GEMM | LN2 -> d_out (fp32)
// GEMM: C = A @ W^T + bias, 128x128 tile, 256 thr (2x2 waves of 64x64), BK=32,
// mfma_f32_16x16x32_bf16, global_load_lds width=16 staging.
// R2: LDS dbuf + source-permuted swizzle (SQ_LDS_BANK_CONFLICT 8.4M->0).
// R3: XCD-aware block swizzle. R4: LDS epilogue + tanh-gelu.
// R5: MFMA attention. R6: 32KB LDS, launch_bounds(256,4), fused cvt.
// R7: SWAPPED-OPERAND MFMA: acc = mfma(W_frag, X_frag, .) -> D-layout gives
//     each lane 4 consecutive output COLS (quad*4+r) at fixed row (lane&15).
//     Epilogue = regs -> packed 8B global stores (sector-complete 32B segs);
//     the whole LDS C-tile round-trip + barrier is deleted (~700 cyc/block).

typedef unsigned short u16;
typedef unsigned int u32;
typedef __attribute__((ext_vector_type(4))) float f32x4;
typedef __attribute__((ext_vector_type(8))) __bf16 bf16x8;

#define DEV static __device__ __forceinline__

DEV u16 f2b(float f) {
  u32 u = __builtin_bit_cast(u32, f);
  u32 r = (u + 0x7FFFu + ((u >> 16) & 1u)) >> 16;
  return (u16)r;
}
DEV float b2f(u16 b) { return __builtin_bit_cast(float, (u32)b << 16); }

DEV void gld16(const u16* g, u16* l) {
  __builtin_amdgcn_global_load_lds(
      (const __attribute__((address_space(1))) u32*)g,
      (__attribute__((address_space(3))) u32*)l, 16, 0, 0);
}

DEV bf16x8 frag8(const u16* p) {
  return __builtin_bit_cast(bf16x8, *(const uint4*)p);
}

// ---------------- fused fp32 -> bf16 convert (5 regions, 8 elems/thread) ----
struct Cvt5 {
  const float *s0, *s1, *s2, *s3, *s4;
  u16 *d0, *d1, *d2, *d3, *d4;
};
__global__ __launch_bounds__(256) void cvt5_kernel(Cvt5 a) {
  int i = blockIdx.x * 256 + threadIdx.x;
  const float* s;
  u16* d;
  int j = i;
  if (i < 1048576) { s = a.s0; d = a.d0; }
  else if (i < 1441792) { s = a.s1; d = a.d1; j = i - 1048576; }
  else if (i < 1572864) { s = a.s2; d = a.d2; j = i - 1441792; }
  else if (i < 2097152) { s = a.s3; d = a.d3; j = i - 1572864; }
  else { s = a.s4; d = a.d4; j = i - 2097152; }
  const float4* p = (const float4*)s + (size_t)j * 2;
  float4 va = p[0], vb = p[1];
  union { u16 s[8]; uint4 u; } o;
  o.s[0] = f2b(va.x); o.s[1] = f2b(va.y); o.s[2] = f2b(va.z); o.s[3] = f2b(va.w);
  o.s[4] = f2b(vb.x); o.s[5] = f2b(vb.y); o.s[6] = f2b(vb.z); o.s[7] = f2b(vb.w);
  ((uint4*)d)[j] = o.u;
}

// ---------------- bf16 GEMM: C[M,N] = A[M,K] @ B[N,K]^T + bias ----------------
// ACT: 0 = none, 1 = tanh-gelu. Output bf16. gm MUST be 64 (M=8192).
template <int ACT>
__global__ __launch_bounds__(256, 4) void gemm_bt(
    const u16* __restrict__ A, const u16* __restrict__ Bm,
    const float* __restrict__ bias, u16* __restrict__ C,
    int N, int K) {
  const int blk = blockIdx.x;
  const int xcd = blk & 7;
  const int j = blk >> 3;
  const int tm = xcd * 8 + (j & 7);
  const int tn = j >> 3;

  __shared__ __align__(16) u16 smem[16384];  // exactly 32 KB
  u16* As = smem;          // [2][4096]
  u16* Bs = smem + 8192;   // [2][4096]

  const int tid = threadIdx.x;
  const int lane = tid & 63;
  const int wave = tid >> 6;
  const int wm = wave >> 1, wn = wave & 1;

  f32x4 acc[4][4] = {};

  const int c0 = tid, c1 = tid + 256;
  const int r0 = c0 >> 2, r1 = c1 >> 2;
  const int s0 = ((c0 & 3) - (r0 >> 1)) & 3;
  const int s1 = ((c1 & 3) - (r1 >> 1)) & 3;
  const u16* ga0 = A + (size_t)(tm * 128 + r0) * K + s0 * 8;
  const u16* ga1 = A + (size_t)(tm * 128 + r1) * K + s1 * 8;
  const u16* gb0 = Bm + (size_t)(tn * 128 + r0) * K + s0 * 8;
  const u16* gb1 = Bm + (size_t)(tn * 128 + r1) * K + s1 * 8;
  const int lo0 = wave * 512;
  const int lo1 = 2048 + wave * 512;

  const int frow = lane & 15;
  const int quad = lane >> 4;
  const int ksw = (quad + (frow >> 1)) & 3;
  const int aoff = (wm * 64 + frow) * 32 + ksw * 8;
  const int boff = (wn * 64 + frow) * 32 + ksw * 8;

  const int nIter = K >> 5;
  gld16(ga0, &As[lo0]);
  gld16(ga1, &As[lo1]);
  gld16(gb0, &Bs[lo0]);
  gld16(gb1, &Bs[lo1]);
  ga0 += 32; ga1 += 32; gb0 += 32; gb1 += 32;
  __syncthreads();

  for (int kt = 0; kt < nIter; kt++) {
    const int p = (kt & 1) * 4096, q = p ^ 4096;
    if (kt + 1 < nIter) {
      gld16(ga0, &As[q + lo0]);
      gld16(ga1, &As[q + lo1]);
      gld16(gb0, &Bs[q + lo0]);
      gld16(gb1, &Bs[q + lo1]);
      ga0 += 32; ga1 += 32; gb0 += 32; gb1 += 32;
    }
    bf16x8 af[4], bq[4];
#pragma unroll
    for (int i = 0; i < 4; i++) af[i] = frag8(&As[p + aoff + i * 512]);
#pragma unroll
    for (int i = 0; i < 4; i++) bq[i] = frag8(&Bs[p + boff + i * 512]);
    // swapped operands: D[w_row][x_row] -> lane&15 = x-row (out row),
    // quad*4+r = w-row (out col)
#pragma unroll
    for (int mt = 0; mt < 4; mt++)
#pragma unroll
      for (int nt = 0; nt < 4; nt++)
        acc[mt][nt] = __builtin_amdgcn_mfma_f32_16x16x32_bf16(
            bq[nt], af[mt], acc[mt][nt], 0, 0, 0);
    __syncthreads();
  }

  // ---- epilogue: regs -> packed 8B stores (4 consecutive cols per lane)
  const int row_b = tm * 128 + wm * 64 + frow;      // + mt*16
  const int col_b = tn * 128 + wn * 64 + quad * 4;  // + nt*16
#pragma unroll
  for (int nt = 0; nt < 4; nt++) {
    const int col = col_b + nt * 16;
    const float4 bv = *(const float4*)&bias[col];
    const float bvr[4] = {bv.x, bv.y, bv.z, bv.w};
#pragma unroll
    for (int mt = 0; mt < 4; mt++) {
      union { u16 s[4]; uint2 u; } o;
#pragma unroll
      for (int r = 0; r < 4; r++) {
        float v = acc[mt][nt][r] + bvr[r];
        if (ACT == 1) {
          float y = 0.7978845608028654f * (v + 0.044715f * v * v * v);
          float t = 1.f - 2.f / (1.f + __expf(2.f * y));  // tanh(y)
          v = 0.5f * v * (1.f + t);
        }
        o.s[r] = f2b(v);
      }
      *(uint2*)&C[(size_t)(row_b + mt * 16) * N + col] = o.u;
    }
  }
}

// ---------------- MFMA attention: one block per (b,h) ----------------
__global__ __launch_bounds__(256) void attn_kernel(
    const u16* __restrict__ qkv, const float* __restrict__ rel,
    u16* __restrict__ ctx) {
  __shared__ __align__(16) u16 qs[4096];
  __shared__ __align__(16) u16 ks[4096];
  __shared__ __align__(16) u16 vt[64 * 72];      // V^T [hd][key], pad 72
  __shared__ __align__(16) u16 ps[4 * 16 * 72];  // per-wave P [q][key], pad 72
  const int tid = threadIdx.x;
  const int lane = tid & 63;
  const int wave = tid >> 6;
  const int quad = lane >> 4;
  const int l15 = lane & 15;
  const int bh = blockIdx.x;
  const int b = bh >> 4, h = bh & 15;
  const size_t base = (size_t)b * 64 * 3072 + h * 64;

  {
    const int cA = tid, cB = tid + 256;
    const int rA = cA >> 3, sA = ((cA & 7) - rA) & 7;
    const int rB = cB >> 3, sB = ((cB & 7) - rB) & 7;
    const u16* gA = qkv + base + (size_t)rA * 3072 + sA * 8;
    const u16* gB = qkv + base + (size_t)rB * 3072 + sB * 8;
    gld16(gA, &qs[wave * 512]);
    gld16(gB, &qs[2048 + wave * 512]);
    gld16(gA + 1024, &ks[wave * 512]);
    gld16(gB + 1024, &ks[2048 + wave * 512]);
  }
  {
    const int hd = tid & 63;
    const int kg0 = tid >> 6;
#pragma unroll
    for (int half = 0; half < 2; half++) {
      const int kg = kg0 + half * 4;
      union { u16 s[8]; uint4 u; } o;
#pragma unroll
      for (int t = 0; t < 8; t++)
        o.s[t] = qkv[base + (size_t)(kg * 8 + t) * 3072 + 2048 + hd];
      *(uint4*)&vt[hd * 72 + kg * 8] = o.u;
    }
  }
  __syncthreads();

  const int qrow = wave * 16 + l15;
  bf16x8 aq[2];
#pragma unroll
  for (int kc = 0; kc < 2; kc++)
    aq[kc] = frag8(&qs[qrow * 64 + (((kc * 4 + quad) + qrow) & 7) * 8]);
  f32x4 accs[4] = {};
#pragma unroll
  for (int nt = 0; nt < 4; nt++) {
    const int krow = nt * 16 + l15;
#pragma unroll
    for (int kc = 0; kc < 2; kc++) {
      bf16x8 bk = frag8(&ks[krow * 64 + (((kc * 4 + quad) + krow) & 7) * 8]);
      accs[nt] =
          __builtin_amdgcn_mfma_f32_16x16x32_bf16(aq[kc], bk, accs[nt], 0, 0, 0);
    }
  }

  const int qg = wave * 16 + quad * 4;
  float pm[4][4], mx[4], sm[4];
#pragma unroll
  for (int r = 0; r < 4; r++) mx[r] = -1e30f;
#pragma unroll
  for (int nt = 0; nt < 4; nt++) {
    const float* rb = &rel[((size_t)h * 64 + qg) * 64 + nt * 16 + l15];
#pragma unroll
    for (int r = 0; r < 4; r++) {
      float v = accs[nt][r] * 0.125f + rb[r * 64];
      pm[nt][r] = v;
      mx[r] = fmaxf(mx[r], v);
    }
  }
#pragma unroll
  for (int r = 0; r < 4; r++) {
    mx[r] = fmaxf(mx[r], __shfl_xor(mx[r], 1));
    mx[r] = fmaxf(mx[r], __shfl_xor(mx[r], 2));
    mx[r] = fmaxf(mx[r], __shfl_xor(mx[r], 4));
    mx[r] = fmaxf(mx[r], __shfl_xor(mx[r], 8));
    sm[r] = 0.f;
  }
#pragma unroll
  for (int nt = 0; nt < 4; nt++)
#pragma unroll
    for (int r = 0; r < 4; r++) {
      float e = __expf(pm[nt][r] - mx[r]);
      pm[nt][r] = e;
      sm[r] += e;
    }
#pragma unroll
  for (int r = 0; r < 4; r++) {
    sm[r] += __shfl_xor(sm[r], 1);
    sm[r] += __shfl_xor(sm[r], 2);
    sm[r] += __shfl_xor(sm[r], 4);
    sm[r] += __shfl_xor(sm[r], 8);
    sm[r] = 1.f / sm[r];
  }
  u16* psw = &ps[wave * 1152];
#pragma unroll
  for (int nt = 0; nt < 4; nt++)
#pragma unroll
    for (int r = 0; r < 4; r++)
      psw[(quad * 4 + r) * 72 + nt * 16 + l15] = f2b(pm[nt][r] * sm[r]);
  __syncthreads();

  bf16x8 ap[2];
#pragma unroll
  for (int kc = 0; kc < 2; kc++)
    ap[kc] = frag8(&psw[l15 * 72 + kc * 32 + quad * 8]);
  f32x4 accc[4] = {};
#pragma unroll
  for (int nt = 0; nt < 4; nt++) {
    const int hdr = nt * 16 + l15;
#pragma unroll
    for (int kc = 0; kc < 2; kc++) {
      bf16x8 bv = frag8(&vt[hdr * 72 + kc * 32 + quad * 8]);
      accc[nt] =
          __builtin_amdgcn_mfma_f32_16x16x32_bf16(ap[kc], bv, accc[nt], 0, 0, 0);
    }
  }
#pragma unroll
  for (int nt = 0; nt < 4; nt++)
#pragma unroll
    for (int r = 0; r < 4; r++) {
      const int rowq = wave * 16 + quad * 4 + r;
      const int hd = nt * 16 + l15;
      qs[rowq * 64 + (((hd >> 3) + rowq) & 7) * 8 + (hd & 7)] = f2b(accc[nt][r]);
    }
  __syncthreads();
#pragma unroll
  for (int half = 0; half < 2; half++) {
    const int c = tid + half * 256;
    const int row = c >> 3, sub = c & 7;
    uint4 val = *(const uint4*)&qs[row * 64 + ((sub + row) & 7) * 8];
    *(uint4*)&ctx[(size_t)(b * 64 + row) * 1024 + h * 64 + sub * 8] = val;
  }
}

// ---------------- LN1: x1 = LN(x_bf16 + attn_bf16) -> bf16 ----------------
__global__ __launch_bounds__(256) void ln1_kernel(
    const u16* __restrict__ xres, const u16* __restrict__ add,
    const float* __restrict__ g, const float* __restrict__ be,
    u16* __restrict__ out) {
  const int row = blockIdx.x * 4 + (threadIdx.x >> 6);
  const int lane = threadIdx.x & 63;
  const u16* xr = xres + (size_t)row * 1024;
  const u16* ar = add + (size_t)row * 1024;
  float v[16];
  float sum = 0.f, sq = 0.f;
#pragma unroll
  for (int kk = 0; kk < 2; kk++) {
    const int cb = (lane + 64 * kk) * 8;
    uint4 xu = *(const uint4*)&xr[cb];
    uint4 au = *(const uint4*)&ar[cb];
    const u16* x8 = (const u16*)&xu;
    const u16* a8 = (const u16*)&au;
#pragma unroll
    for (int t = 0; t < 8; t++) {
      float f = b2f(x8[t]) + b2f(a8[t]);
      v[kk * 8 + t] = f;
      sum += f;
      sq += f * f;
    }
  }
#pragma unroll
  for (int o = 1; o < 64; o <<= 1) {
    sum += __shfl_xor(sum, o);
    sq += __shfl_xor(sq, o);
  }
  const float mean = sum * (1.f / 1024.f);
  const float var = sq * (1.f / 1024.f) - mean * mean;
  const float rstd = rsqrtf(var + 1e-5f);
#pragma unroll
  for (int kk = 0; kk < 2; kk++) {
    const int cb = (lane + 64 * kk) * 8;
    float4 ga = *(const float4*)&g[cb];
    float4 gb = *(const float4*)&g[cb + 4];
    float4 ba = *(const float4*)&be[cb];
    float4 bb = *(const float4*)&be[cb + 4];
    const float* vv = &v[kk * 8];
    union { u16 s[8]; uint4 u; } o8;
    o8.s[0] = f2b((vv[0] - mean) * rstd * ga.x + ba.x);
    o8.s[1] = f2b((vv[1] - mean) * rstd * ga.y + ba.y);
    o8.s[2] = f2b((vv[2] - mean) * rstd * ga.z + ba.z);
    o8.s[3] = f2b((vv[3] - mean) * rstd * ga.w + ba.w);
    o8.s[4] = f2b((vv[4] - mean) * rstd * gb.x + bb.x);
    o8.s[5] = f2b((vv[5] - mean) * rstd * gb.y + bb.y);
    o8.s[6] = f2b((vv[6] - mean) * rstd * gb.z + bb.z);
    o8.s[7] = f2b((vv[7] - mean) * rstd * gb.w + bb.w);
    *(uint4*)&out[(size_t)row * 1024 + cb] = o8.u;
  }
}

// ---------------- LN2: out = LN(x1_bf16 + ffn_bf16) -> fp32 (d_out) --------
__global__ __launch_bounds__(256) void ln2_kernel(
    const u16* __restrict__ xres, const u16* __restrict__ add,
    const float* __restrict__ g, const float* __restrict__ be,
    float* __restrict__ out) {
  const int row = blockIdx.x * 4 + (threadIdx.x >> 6);
  const int lane = threadIdx.x & 63;
  const u16* xr = xres + (size_t)row * 1024;
  const u16* ar = add + (size_t)row * 1024;
  float v[16];
  float sum = 0.f, sq = 0.f;
#pragma unroll
  for (int kk = 0; kk < 2; kk++) {
    const int cb = (lane + 64 * kk) * 8;
    uint4 xu = *(const uint4*)&xr[cb];
    uint4 au = *(const uint4*)&ar[cb];
    const u16* x8 = (const u16*)&xu;
    const u16* a8 = (const u16*)&au;
#pragma unroll
    for (int t = 0; t < 8; t++) {
      float f = b2f(x8[t]) + b2f(a8[t]);
      v[kk * 8 + t] = f;
      sum += f;
      sq += f * f;
    }
  }
#pragma unroll
  for (int o = 1; o < 64; o <<= 1) {
    sum += __shfl_xor(sum, o);
    sq += __shfl_xor(sq, o);
  }
  const float mean = sum * (1.f / 1024.f);
  const float var = sq * (1.f / 1024.f) - mean * mean;
  const float rstd = rsqrtf(var + 1e-5f);
#pragma unroll
  for (int kk = 0; kk < 2; kk++) {
    const int cb = (lane + 64 * kk) * 8;
    float4 ga = *(const float4*)&g[cb];
    float4 gb = *(const float4*)&g[cb + 4];
    float4 ba = *(const float4*)&be[cb];
    float4 bb = *(const float4*)&be[cb + 4];
    float4 o0, o1;
    o0.x = (v[kk * 8 + 0] - mean) * rstd * ga.x + ba.x;
    o0.y = (v[kk * 8 + 1] - mean) * rstd * ga.y + ba.y;
    o0.z = (v[kk * 8 + 2] - mean) * rstd * ga.z + ba.z;
    o0.w = (v[kk * 8 + 3] - mean) * rstd * ga.w + ba.w;
    o1.x = (v[kk * 8 + 4] - mean) * rstd * gb.x + bb.x;
    o1.y = (v[kk * 8 + 5] - mean) * rstd * gb.y + bb.y;
    o1.z = (v[kk * 8 + 6] - mean) * rstd * gb.z + bb.z;
    o1.w = (v[kk * 8 + 7] - mean) * rstd * gb.w + bb.w;
    *(float4*)&out[(size_t)row * 1024 + cb] = o0;
    *(float4*)&out[(size_t)row * 1024 + cb + 4] = o1;
  }
}

extern "C" void kernel_launch(void* const* d_in, const int* in_sizes, int n_in,
                              void* d_out, int out_size, void* d_ws,
                              size_t ws_size, hipStream_t stream) {
  const float* x = (const float*)d_in[0];
  const float* w_in = (const float*)d_in[1];
  const float* b_in = (const float*)d_in[2];
  const float* w_out = (const float*)d_in[3];
  const float* b_out = (const float*)d_in[4];
  const float* rel = (const float*)d_in[5];
  const float* g1 = (const float*)d_in[6];
  const float* be1 = (const float*)d_in[7];
  const float* w1 = (const float*)d_in[8];
  const float* b1 = (const float*)d_in[9];
  const float* w2 = (const float*)d_in[10];
  const float* b2 = (const float*)d_in[11];
  const float* g2 = (const float*)d_in[12];
  const float* be2 = (const float*)d_in[13];
  float* out = (float*)d_out;

  u16* ws = (u16*)d_ws;
  u16* xb = ws + 0;            // 8,388,608
  u16* winb = ws + 8388608;    // 3,145,728
  u16* woutb = ws + 11534336;  // 1,048,576
  u16* w1b = ws + 12582912;    // 4,194,304
  u16* w2b = ws + 16777216;    // 4,194,304
  u16* qkvb = ws + 20971520;   // 25,165,824  (h aliases qkv+ctx)
  u16* ctxb = ws + 46137344;   // 8,388,608
  u16* attnb = ws + 54525952;  // 8,388,608   (ffn aliases)
  u16* x1b = ws + 62914560;    // 8,388,608
  u16* hb = qkvb;
  u16* ffnb = attnb;

  Cvt5 ca;
  ca.s0 = x; ca.s1 = w_in; ca.s2 = w_out; ca.s3 = w1; ca.s4 = w2;
  ca.d0 = xb; ca.d1 = winb; ca.d2 = woutb; ca.d3 = w1b; ca.d4 = w2b;
  cvt5_kernel<<<10240, 256, 0, stream>>>(ca);

  gemm_bt<0><<<64 * 24, 256, 0, stream>>>(xb, winb, b_in, qkvb, 3072, 1024);

  attn_kernel<<<2048, 256, 0, stream>>>(qkvb, rel, ctxb);

  gemm_bt<0><<<64 * 8, 256, 0, stream>>>(ctxb, woutb, b_out, attnb, 1024, 1024);

  ln1_kernel<<<2048, 256, 0, stream>>>(xb, attnb, g1, be1, x1b);

  gemm_bt<1><<<64 * 32, 256, 0, stream>>>(x1b, w1b, b1, hb, 4096, 1024);

  gemm_bt<0><<<64 * 8, 256, 0, stream>>>(hb, w2b, b2, ffnb, 1024, 4096);

  ln2_kernel<<<2048, 256, 0, stream>>>(x1b, ffnb, g2, be2, out);
}